// Round 2
// baseline (280.695 us; speedup 1.0000x reference)
//
#include <hip/hip_runtime.h>
#include <hip/hip_bf16.h>
#include <math.h>

// Problem constants (from setup_inputs)
#define BB 8
#define QN 512
#define SN 64
#define TN 128
#define DD 128
#define STAT_K 8
#define TOK_K 16
#define SCALE 0.08838834764831845f   // 1/sqrt(128)
#define NEGBIG -1e6f
#define NINF  -3.4e38f

typedef float f4 __attribute__((ext_vector_type(4)));

// ---------------------------------------------------------------------------
// Projection GEMM: C[M,128] = A[M,128] @ W[128,128], fp32.
// 128 rows/block, 256 threads, 8x8 per-thread tile. Only W staged in LDS
// (64 KB -> 2 blocks/CU); A-fragments are 16-lane broadcast loads from L1/L2.
// transposeBlk: per-128-row-block transposed output C[blk][col][row%128].
// ---------------------------------------------------------------------------
__global__ __launch_bounds__(256) void proj_gemm(const float* __restrict__ A,
                                                 const float* __restrict__ W,
                                                 float* __restrict__ C,
                                                 int transposeBlk)
{
    __shared__ float Ws[128 * 128];   // 64 KB
    const int tid = threadIdx.x;
    const size_t rowBase = (size_t)blockIdx.x * 128;

    #pragma unroll
    for (int i = 0; i < 16; ++i) {
        int idx = i * 256 + tid;          // 0..4095 float4 slots
        ((f4*)Ws)[idx] = ((const f4*)W)[idx];
    }
    __syncthreads();

    const int tx = tid & 15;    // cols tx*4..+3 and 64+tx*4..+3
    const int ty = tid >> 4;    // rows ty*8..+7
    const float* Ab = A + (rowBase + ty * 8) * 128;

    float acc[8][8];
    #pragma unroll
    for (int i = 0; i < 8; ++i)
        #pragma unroll
        for (int j = 0; j < 8; ++j) acc[i][j] = 0.f;

    #pragma unroll 2
    for (int k0 = 0; k0 < 128; k0 += 4) {
        f4 a[8];
        #pragma unroll
        for (int i = 0; i < 8; ++i)
            a[i] = *(const f4*)(Ab + i * 128 + k0);    // 16-lane broadcast
        f4 wl[4], wh[4];
        #pragma unroll
        for (int kk = 0; kk < 4; ++kk) {
            wl[kk] = *(const f4*)&Ws[(k0 + kk) * 128 + tx * 4];
            wh[kk] = *(const f4*)&Ws[(k0 + kk) * 128 + 64 + tx * 4];
        }
        #pragma unroll
        for (int i = 0; i < 8; ++i)
            #pragma unroll
            for (int kk = 0; kk < 4; ++kk)
                #pragma unroll
                for (int j = 0; j < 4; ++j) {
                    acc[i][j]     = fmaf(a[i][kk], wl[kk][j], acc[i][j]);
                    acc[i][4 + j] = fmaf(a[i][kk], wh[kk][j], acc[i][4 + j]);
                }
    }

    if (!transposeBlk) {
        #pragma unroll
        for (int i = 0; i < 8; ++i) {
            size_t row = rowBase + ty * 8 + i;
            f4 lo = {acc[i][0], acc[i][1], acc[i][2], acc[i][3]};
            f4 hi = {acc[i][4], acc[i][5], acc[i][6], acc[i][7]};
            *(f4*)&C[row * 128 + tx * 4]      = lo;
            *(f4*)&C[row * 128 + 64 + tx * 4] = hi;
        }
    } else {
        float* Cb = C + ((size_t)blockIdx.x << 14);   // blk * 128*128
        #pragma unroll
        for (int j = 0; j < 4; ++j) {
            int clo = tx * 4 + j;
            int chi = 64 + tx * 4 + j;
            f4 v0 = {acc[0][j], acc[1][j], acc[2][j], acc[3][j]};
            f4 v1 = {acc[4][j], acc[5][j], acc[6][j], acc[7][j]};
            *(f4*)&Cb[clo * 128 + ty * 8]     = v0;
            *(f4*)&Cb[clo * 128 + ty * 8 + 4] = v1;
            f4 v2 = {acc[0][4 + j], acc[1][4 + j], acc[2][4 + j], acc[3][4 + j]};
            f4 v3 = {acc[4][4 + j], acc[5][4 + j], acc[6][4 + j], acc[7][4 + j]};
            *(f4*)&Cb[chi * 128 + ty * 8]     = v2;
            *(f4*)&Cb[chi * 128 + ty * 8 + 4] = v3;
        }
    }
}

// ---------------------------------------------------------------------------
// Stat level: one wave per (b,q), lane = stat s. Top-8 + softmax (exact jax
// tie-break: lowest index). Invalid stats -> exp underflows to exactly 0.
// ---------------------------------------------------------------------------
__global__ __launch_bounds__(64, 4) void stat_topk(const float* __restrict__ qs,
                                                   const float* __restrict__ ks,
                                                   const int* __restrict__ vlen,
                                                   int* __restrict__ sel_i,
                                                   float* __restrict__ sel_w)
{
    const int bq   = blockIdx.x;
    const int b    = bq >> 9;
    const int lane = threadIdx.x;

    const f4* q4 = (const f4*)(qs + (size_t)bq * 128);
    const f4* k4 = (const f4*)(ks + (size_t)(b * SN + lane) * 128);
    float acc = 0.f;
    #pragma unroll 8
    for (int kk = 0; kk < 32; ++kk) {
        f4 q = q4[kk];
        f4 k = k4[kk];
        acc = fmaf(q[0], k[0], acc);
        acc = fmaf(q[1], k[1], acc);
        acc = fmaf(q[2], k[2], acc);
        acc = fmaf(q[3], k[3], acc);
    }
    float score = acc * SCALE;
    if (lane >= vlen[b]) score = NEGBIG;

    float work = score;
    float tv[STAT_K];
    int   ti[STAT_K];
    #pragma unroll
    for (int j = 0; j < STAT_K; ++j) {
        float m = work;
        #pragma unroll
        for (int off = 32; off > 0; off >>= 1) m = fmaxf(m, __shfl_xor(m, off));
        unsigned long long ball = __ballot(work == m);
        int L = __ffsll(ball) - 1;
        tv[j] = m;
        ti[j] = L;
        if (lane == L) work = NINF;
    }

    float w[STAT_K];
    float Z = 0.f;
    #pragma unroll
    for (int j = 0; j < STAT_K; ++j) { w[j] = expf(tv[j] - tv[0]); Z += w[j]; }
    float invZ = 1.f / Z;

    if (lane < STAT_K) {
        sel_i[(size_t)bq * STAT_K + lane] = ti[lane];
        sel_w[(size_t)bq * STAT_K + lane] = w[lane] * invZ;
    }
}

// ---------------------------------------------------------------------------
// Zero the atomic-accumulated output and the bin counters.
// ---------------------------------------------------------------------------
__global__ void zero_misc(float* __restrict__ out_pre, int* __restrict__ cnt)
{
    int idx = blockIdx.x * 256 + threadIdx.x;    // 512*256 = 131072 f4 = 2 MB
    f4 z = {0.f, 0.f, 0.f, 0.f};
    ((f4*)out_pre)[idx] = z;
    if (idx < BB * SN) cnt[idx] = 0;
}

// ---------------------------------------------------------------------------
// Bin (query, si) pairs by selected stat block (b,s). sw==0 pairs contribute
// exactly 0 -> skipped entirely.
// ---------------------------------------------------------------------------
__global__ void bin_build(const int* __restrict__ sel_i,
                          const float* __restrict__ sel_w,
                          int* __restrict__ cnt, int* __restrict__ list)
{
    int idx = blockIdx.x * 256 + threadIdx.x;    // bq*8+si, 32768 total
    if (idx >= BB * QN * STAT_K) return;
    float sw = sel_w[idx];
    if (sw == 0.f) return;
    int bq = idx >> 3, si = idx & 7;
    int b = bq >> 9, q = bq & 511;
    int s = sel_i[idx];
    int bs = b * SN + s;
    int pos = atomicAdd(&cnt[bs], 1);
    list[bs * 512 + pos] = q | (si << 16);
}

// ---------------------------------------------------------------------------
// Token level, binned: block = (b,s,chunk of 64 queries). Stage the (b,s)
// k-block [128 d][128 t] in LDS once; 4 waves x (2 half-waves x 8 queries).
// Per 32-lane half: GEMM-tile scores (lane: 8q x 4t, d-quads), exact top-16
// (iterative half-wave max, lowest-index ties), softmax, PV f4 gather,
// atomicAdd into out_pre.
// ---------------------------------------------------------------------------
__global__ __launch_bounds__(256) void tok_binned(const float* __restrict__ qt,
                                                  const float* __restrict__ kT,
                                                  const float* __restrict__ v,
                                                  const int* __restrict__ cnt,
                                                  const int* __restrict__ list,
                                                  const float* __restrict__ sel_w,
                                                  float* __restrict__ out_pre)
{
    const int bsIdx = blockIdx.x & 511;
    const int chunk = blockIdx.x >> 9;
    const int b  = bsIdx & 7;          // fast-varying batch -> XCD spread
    const int s  = bsIdx >> 3;
    const int bs = b * SN + s;
    const int nq = cnt[bs];
    const int q0 = chunk * 64;
    if (q0 >= nq) return;
    const int nhere = min(64, nq - q0);

    __shared__ float ksh[128 * 128];   // 64 KB, [d][t]
    const int tid = threadIdx.x;
    {
        const f4* src = (const f4*)(kT + ((size_t)bs << 14));
        #pragma unroll
        for (int i = 0; i < 16; ++i)
            ((f4*)ksh)[i * 256 + tid] = src[i * 256 + tid];
    }
    __syncthreads();

    const int wid  = tid >> 6;
    const int lane = tid & 63;
    const int qg   = lane >> 5;        // independent 32-lane half
    const int tg   = lane & 31;        // tokens tg*4..tg*4+3

    if (wid * 16 >= nhere) return;     // wave has no queries (after barrier)

    const int base = wid * 16 + qg * 8;
    int   qrow[8], sidx[8];
    float swq[8];
    bool  vld[8];
    #pragma unroll
    for (int i = 0; i < 8; ++i) {
        bool ok = (base + i) < nhere;
        int e = ok ? list[bs * 512 + q0 + base + i] : 0;
        qrow[i] = e & 0xffff;
        sidx[i] = (e >> 16) & 7;
        swq[i]  = ok ? sel_w[((size_t)(b * QN + qrow[i])) * STAT_K + sidx[i]] : 0.f;
        vld[i]  = ok;
    }

    // ---- scores: acc[i][j] = sum_d q[i][d] * k[d][tg*4+j], d ascending ----
    float acc[8][4];
    #pragma unroll
    for (int i = 0; i < 8; ++i)
        #pragma unroll
        for (int j = 0; j < 4; ++j) acc[i][j] = 0.f;

    #pragma unroll 2
    for (int dq = 0; dq < 128; dq += 4) {
        f4 kf[4];
        #pragma unroll
        for (int kk = 0; kk < 4; ++kk)
            kf[kk] = *(const f4*)&ksh[(dq + kk) * 128 + tg * 4];
        f4 qv[8];
        #pragma unroll
        for (int i = 0; i < 8; ++i)
            qv[i] = *(const f4*)(qt + ((size_t)(b * QN + qrow[i])) * 128 + dq);
        #pragma unroll
        for (int i = 0; i < 8; ++i)
            #pragma unroll
            for (int kk = 0; kk < 4; ++kk)
                #pragma unroll
                for (int j = 0; j < 4; ++j)
                    acc[i][j] = fmaf(qv[i][kk], kf[kk][j], acc[i][j]);
    }

    const float* vb = v + ((size_t)bs << 14);

    // ---- per query: top-16, softmax, PV gather, atomic output ----
    #pragma unroll
    for (int i = 0; i < 8; ++i) {
        if (!vld[i]) continue;         // half-uniform branch

        float w0 = acc[i][0] * SCALE;
        float w1 = acc[i][1] * SCALE;
        float w2 = acc[i][2] * SCALE;
        float w3 = acc[i][3] * SCALE;

        float tv[TOK_K];
        int   tt[TOK_K];
        #pragma unroll
        for (int j = 0; j < TOK_K; ++j) {
            float lm = fmaxf(fmaxf(w0, w1), fmaxf(w2, w3));
            float m = lm;
            #pragma unroll
            for (int off = 16; off > 0; off >>= 1) m = fmaxf(m, __shfl_xor(m, off));
            unsigned int ball = (unsigned int)(__ballot(lm == m) >> (qg * 32));
            int L = __ffs(ball) - 1;                       // lane-in-half, lowest tg
            int r = (w0 == m) ? 0 : ((w1 == m) ? 1 : ((w2 == m) ? 2 : 3));
            int tok = __shfl(tg * 4 + r, qg * 32 + L);
            tv[j] = m;
            tt[j] = tok;
            bool win = ((lane & 31) == L);
            w0 = (win && r == 0) ? NINF : w0;
            w1 = (win && r == 1) ? NINF : w1;
            w2 = (win && r == 2) ? NINF : w2;
            w3 = (win && r == 3) ? NINF : w3;
        }

        float pw[TOK_K];
        float Z = 0.f;
        #pragma unroll
        for (int j = 0; j < TOK_K; ++j) { pw[j] = expf(tv[j] - tv[0]); Z += pw[j]; }
        float cs = swq[i] / Z;          // fold stat weight into combine weight

        f4 o = {0.f, 0.f, 0.f, 0.f};
        #pragma unroll
        for (int j = 0; j < TOK_K; ++j) {
            f4 vr = *(const f4*)(vb + (size_t)tt[j] * 128 + tg * 4);
            float cw = pw[j] * cs;
            o[0] = fmaf(cw, vr[0], o[0]);
            o[1] = fmaf(cw, vr[1], o[1]);
            o[2] = fmaf(cw, vr[2], o[2]);
            o[3] = fmaf(cw, vr[3], o[3]);
        }

        float* op = out_pre + (size_t)(b * QN + qrow[i]) * 128 + tg * 4;
        atomicAdd(op + 0, o[0]);
        atomicAdd(op + 1, o[1]);
        atomicAdd(op + 2, o[2]);
        atomicAdd(op + 3, o[3]);
    }
}

// ---------------------------------------------------------------------------
extern "C" void kernel_launch(void* const* d_in, const int* in_sizes, int n_in,
                              void* d_out, int out_size, void* d_ws, size_t ws_size,
                              hipStream_t stream)
{
    const float* queries    = (const float*)d_in[0];
    const float* stat_keys  = (const float*)d_in[1];
    const float* token_keys = (const float*)d_in[2];
    const float* values     = (const float*)d_in[3];
    const int*   vlen       = (const int*)d_in[4];
    const float* Wq_stat    = (const float*)d_in[5];
    const float* Wq_token   = (const float*)d_in[6];
    const float* Wk_stat    = (const float*)d_in[7];
    const float* Wk_token   = (const float*)d_in[8];
    const float* Wv         = (const float*)d_in[9];
    const float* Wo         = (const float*)d_in[10];

    char* ws = (char*)d_ws;
    float* q_stat  = (float*)(ws);                 // 2 MB (dead after stat_topk)
    int*   list    = (int*)  (ws);                 // 1 MB, overlays q_stat
    float* q_tok   = (float*)(ws + 2097152);       // 2 MB
    float* k_stat  = (float*)(ws + 4194304);       // 256 KB (dead after stat_topk)
    int*   cnt     = (int*)  (ws + 4194304);       // 2 KB, overlays k_stat
    float* k_tokT  = (float*)(ws + 4456448);       // [512][128d][128t] = 32 MB
    float* v       = (float*)(ws + 38010880);      // 32 MB
    int*   sel_i   = (int*)  (ws + 71565312);      // 128 KB
    float* sel_w   = (float*)(ws + 71696384);      // 128 KB
    float* out_pre = (float*)(ws + 71827456);      // 2 MB  (total 73,924,608 B)

    // Projections (all fp32 -- scores feeding top-k must match fp32 exactly)
    proj_gemm<<<32,  256, 0, stream>>>(queries,    Wq_stat,  q_stat, 0);
    proj_gemm<<<32,  256, 0, stream>>>(queries,    Wq_token, q_tok,  0);
    proj_gemm<<<4,   256, 0, stream>>>(stat_keys,  Wk_stat,  k_stat, 0);
    proj_gemm<<<512, 256, 0, stream>>>(token_keys, Wk_token, k_tokT, 1);
    proj_gemm<<<512, 256, 0, stream>>>(values,     Wv,       v,      0);

    // Stat-level top-8 selection + weights
    stat_topk<<<BB * QN, 64, 0, stream>>>(q_stat, k_stat, vlen, sel_i, sel_w);

    // Zero accumulators/counters, bin queries by selected stat
    zero_misc<<<512, 256, 0, stream>>>(out_pre, cnt);
    bin_build<<<128, 256, 0, stream>>>(sel_i, sel_w, cnt, list);

    // Token-level top-16 + PV, one LDS-staged k-block per (b,s)
    tok_binned<<<4096, 256, 0, stream>>>(q_tok, k_tokT, v, cnt, list, sel_w, out_pre);

    // Output projection
    proj_gemm<<<32, 256, 0, stream>>>(out_pre, Wo, (float*)d_out, 0);
}

// Round 3
// 280.619 us; speedup vs baseline: 1.0003x; 1.0003x over previous
//
#include <hip/hip_runtime.h>
#include <hip/hip_bf16.h>
#include <math.h>

// Problem constants (from setup_inputs)
#define BB 8
#define QN 512
#define SN 64
#define TN 128
#define DD 128
#define STAT_K 8
#define TOK_K 16
#define SCALE 0.08838834764831845f   // 1/sqrt(128)
#define NEGBIG -1e6f
#define NINF  -3.4e38f

typedef float f4 __attribute__((ext_vector_type(4)));

// ---------------------------------------------------------------------------
// 8-rows-per-thread GEMM tile body (128 rows/block, 256 threads).
// W already staged in Ws. transposed: per-128-row-block output C[blk][col][row].
// ---------------------------------------------------------------------------
__device__ __forceinline__ void proj_tile8(const float* __restrict__ A,
                                           const float* __restrict__ Ws,
                                           float* __restrict__ C,
                                           int blk, int transposed, int tid)
{
    const int tx = tid & 15;    // cols tx*4..+3 and 64+tx*4..+3
    const int ty = tid >> 4;    // rows ty*8..+7
    const size_t rowBase = (size_t)blk * 128;
    const float* Ab = A + (rowBase + ty * 8) * 128;

    float acc[8][8];
    #pragma unroll
    for (int i = 0; i < 8; ++i)
        #pragma unroll
        for (int j = 0; j < 8; ++j) acc[i][j] = 0.f;

    #pragma unroll 2
    for (int k0 = 0; k0 < 128; k0 += 4) {
        f4 a[8];
        #pragma unroll
        for (int i = 0; i < 8; ++i)
            a[i] = *(const f4*)(Ab + i * 128 + k0);    // 16-lane broadcast
        f4 wl[4], wh[4];
        #pragma unroll
        for (int kk = 0; kk < 4; ++kk) {
            wl[kk] = *(const f4*)&Ws[(k0 + kk) * 128 + tx * 4];
            wh[kk] = *(const f4*)&Ws[(k0 + kk) * 128 + 64 + tx * 4];
        }
        #pragma unroll
        for (int i = 0; i < 8; ++i)
            #pragma unroll
            for (int kk = 0; kk < 4; ++kk)
                #pragma unroll
                for (int j = 0; j < 4; ++j) {
                    acc[i][j]     = fmaf(a[i][kk], wl[kk][j], acc[i][j]);
                    acc[i][4 + j] = fmaf(a[i][kk], wh[kk][j], acc[i][4 + j]);
                }
    }

    if (!transposed) {
        #pragma unroll
        for (int i = 0; i < 8; ++i) {
            size_t row = rowBase + ty * 8 + i;
            f4 lo = {acc[i][0], acc[i][1], acc[i][2], acc[i][3]};
            f4 hi = {acc[i][4], acc[i][5], acc[i][6], acc[i][7]};
            *(f4*)&C[row * 128 + tx * 4]      = lo;
            *(f4*)&C[row * 128 + 64 + tx * 4] = hi;
        }
    } else {
        float* Cb = C + ((size_t)blk << 14);   // blk * 128*128
        #pragma unroll
        for (int j = 0; j < 4; ++j) {
            int clo = tx * 4 + j;
            int chi = 64 + tx * 4 + j;
            f4 v0 = {acc[0][j], acc[1][j], acc[2][j], acc[3][j]};
            f4 v1 = {acc[4][j], acc[5][j], acc[6][j], acc[7][j]};
            *(f4*)&Cb[clo * 128 + ty * 8]     = v0;
            *(f4*)&Cb[clo * 128 + ty * 8 + 4] = v1;
            f4 v2 = {acc[0][4 + j], acc[1][4 + j], acc[2][4 + j], acc[3][4 + j]};
            f4 v3 = {acc[4][4 + j], acc[5][4 + j], acc[6][4 + j], acc[7][4 + j]};
            *(f4*)&Cb[chi * 128 + ty * 8]     = v2;
            *(f4*)&Cb[chi * 128 + ty * 8 + 4] = v3;
        }
    }
}

// 4-rows-per-thread tile (64 rows/block) for the small GEMMs.
__device__ __forceinline__ void proj_tile4(const float* __restrict__ A,
                                           const float* __restrict__ Ws,
                                           float* __restrict__ C,
                                           int rowBase, int tid)
{
    const int tx = tid & 15;
    const int ty = tid >> 4;   // 0..15, rows ty*4..+3
    const float* Ab = A + (size_t)(rowBase + ty * 4) * 128;

    float acc[4][8];
    #pragma unroll
    for (int i = 0; i < 4; ++i)
        #pragma unroll
        for (int j = 0; j < 8; ++j) acc[i][j] = 0.f;

    #pragma unroll 2
    for (int k0 = 0; k0 < 128; k0 += 4) {
        f4 a[4];
        #pragma unroll
        for (int i = 0; i < 4; ++i)
            a[i] = *(const f4*)(Ab + i * 128 + k0);
        f4 wl[4], wh[4];
        #pragma unroll
        for (int kk = 0; kk < 4; ++kk) {
            wl[kk] = *(const f4*)&Ws[(k0 + kk) * 128 + tx * 4];
            wh[kk] = *(const f4*)&Ws[(k0 + kk) * 128 + 64 + tx * 4];
        }
        #pragma unroll
        for (int i = 0; i < 4; ++i)
            #pragma unroll
            for (int kk = 0; kk < 4; ++kk)
                #pragma unroll
                for (int j = 0; j < 4; ++j) {
                    acc[i][j]     = fmaf(a[i][kk], wl[kk][j], acc[i][j]);
                    acc[i][4 + j] = fmaf(a[i][kk], wh[kk][j], acc[i][4 + j]);
                }
    }
    #pragma unroll
    for (int i = 0; i < 4; ++i) {
        size_t row = (size_t)rowBase + ty * 4 + i;
        f4 lo = {acc[i][0], acc[i][1], acc[i][2], acc[i][3]};
        f4 hi = {acc[i][4], acc[i][5], acc[i][6], acc[i][7]};
        *(f4*)&C[row * 128 + tx * 4]      = lo;
        *(f4*)&C[row * 128 + 64 + tx * 4] = hi;
    }
}

#define STAGE_W(Wp)                                                        \
    {                                                                      \
        _Pragma("unroll")                                                  \
        for (int i_ = 0; i_ < 16; ++i_)                                    \
            ((f4*)Ws)[i_ * 256 + threadIdx.x] =                            \
                ((const f4*)(Wp))[i_ * 256 + threadIdx.x];                 \
        __syncthreads();                                                   \
    }

// Big fused projection: blocks 0..511 -> token_keys@Wk_token -> kT (transposed
// per (b,s) block), blocks 512..1023 -> values@Wv -> v.
__global__ __launch_bounds__(256) void proj8_fused(const float* __restrict__ token_keys,
                                                   const float* __restrict__ values,
                                                   const float* __restrict__ Wk_token,
                                                   const float* __restrict__ Wv,
                                                   float* __restrict__ kT,
                                                   float* __restrict__ v)
{
    __shared__ float Ws[128 * 128];
    const int seg = blockIdx.x >> 9;
    const int blk = blockIdx.x & 511;
    if (seg == 0) {
        STAGE_W(Wk_token);
        proj_tile8(token_keys, Ws, kT, blk, 1, threadIdx.x);
    } else {
        STAGE_W(Wv);
        proj_tile8(values, Ws, v, blk, 0, threadIdx.x);
    }
}

// Small fused projection: 0..63 q_stat, 64..127 q_tok, 128..135 k_stat.
__global__ __launch_bounds__(256) void proj4_small(const float* __restrict__ queries,
                                                   const float* __restrict__ stat_keys,
                                                   const float* __restrict__ Wq_stat,
                                                   const float* __restrict__ Wq_token,
                                                   const float* __restrict__ Wk_stat,
                                                   float* __restrict__ q_stat,
                                                   float* __restrict__ q_tok,
                                                   float* __restrict__ k_stat)
{
    __shared__ float Ws[128 * 128];
    const int bi = blockIdx.x;
    if (bi < 64) {
        STAGE_W(Wq_stat);
        proj_tile4(queries, Ws, q_stat, bi * 64, threadIdx.x);
    } else if (bi < 128) {
        STAGE_W(Wq_token);
        proj_tile4(queries, Ws, q_tok, (bi - 64) * 64, threadIdx.x);
    } else {
        STAGE_W(Wk_stat);
        proj_tile4(stat_keys, Ws, k_stat, (bi - 128) * 64, threadIdx.x);
    }
}

// Output projection: out_pre @ Wo -> d_out (4096 rows, 64 blocks).
__global__ __launch_bounds__(256) void proj4_one(const float* __restrict__ A,
                                                 const float* __restrict__ W,
                                                 float* __restrict__ C)
{
    __shared__ float Ws[128 * 128];
    STAGE_W(W);
    proj_tile4(A, Ws, C, blockIdx.x * 64, threadIdx.x);
}

// ---------------------------------------------------------------------------
// Stat level: one wave per (b,q), lane = stat s. Top-8 + softmax (exact jax
// tie-break: lowest index). Invalid stats -> exp underflows to exactly 0.
// ---------------------------------------------------------------------------
__global__ __launch_bounds__(64, 4) void stat_topk(const float* __restrict__ qs,
                                                   const float* __restrict__ ks,
                                                   const int* __restrict__ vlen,
                                                   int* __restrict__ sel_i,
                                                   float* __restrict__ sel_w)
{
    const int bq   = blockIdx.x;
    const int b    = bq >> 9;
    const int lane = threadIdx.x;

    const f4* q4 = (const f4*)(qs + (size_t)bq * 128);
    const f4* k4 = (const f4*)(ks + (size_t)(b * SN + lane) * 128);
    float acc = 0.f;
    #pragma unroll 8
    for (int kk = 0; kk < 32; ++kk) {
        f4 q = q4[kk];
        f4 k = k4[kk];
        acc = fmaf(q[0], k[0], acc);
        acc = fmaf(q[1], k[1], acc);
        acc = fmaf(q[2], k[2], acc);
        acc = fmaf(q[3], k[3], acc);
    }
    float score = acc * SCALE;
    if (lane >= vlen[b]) score = NEGBIG;

    float work = score;
    float tv[STAT_K];
    int   ti[STAT_K];
    #pragma unroll
    for (int j = 0; j < STAT_K; ++j) {
        float m = work;
        #pragma unroll
        for (int off = 32; off > 0; off >>= 1) m = fmaxf(m, __shfl_xor(m, off));
        unsigned long long ball = __ballot(work == m);
        int L = __ffsll(ball) - 1;     // lowest index wins ties
        tv[j] = m;
        ti[j] = L;
        if (lane == L) work = NINF;
    }

    float w[STAT_K];
    float Z = 0.f;
    #pragma unroll
    for (int j = 0; j < STAT_K; ++j) { w[j] = expf(tv[j] - tv[0]); Z += w[j]; }
    float invZ = 1.f / Z;

    if (lane < STAT_K) {
        sel_i[(size_t)bq * STAT_K + lane] = ti[lane];
        sel_w[(size_t)bq * STAT_K + lane] = w[lane] * invZ;
    }
}

// ---------------------------------------------------------------------------
__global__ void zero_misc(float* __restrict__ out_pre, int* __restrict__ cnt)
{
    int idx = blockIdx.x * 256 + threadIdx.x;    // 512*256 = 131072 f4 = 2 MB
    f4 z = {0.f, 0.f, 0.f, 0.f};
    ((f4*)out_pre)[idx] = z;
    if (idx < BB * SN) cnt[idx] = 0;
}

__global__ void bin_build(const int* __restrict__ sel_i,
                          const float* __restrict__ sel_w,
                          int* __restrict__ cnt, int* __restrict__ list)
{
    int idx = blockIdx.x * 256 + threadIdx.x;    // bq*8+si, 32768 total
    if (idx >= BB * QN * STAT_K) return;
    float sw = sel_w[idx];
    if (sw == 0.f) return;                       // exactly-zero contribution
    int bq = idx >> 3, si = idx & 7;
    int b = bq >> 9, q = bq & 511;
    int s = sel_i[idx];
    int bs = b * SN + s;
    int pos = atomicAdd(&cnt[bs], 1);
    list[bs * 512 + pos] = q | (si << 16);
}

// ---------------------------------------------------------------------------
// Token level fused: ONE WAVE per (bin, 64-query chunk).
// Phase A: scores in GEMM layout (k from L2), written XOR-swizzled to LDS.
// Phase B: lane = query; branch-free 16-deep insertion top-16 (no cross-lane
//          ops at all; strict > on ascending t == jax lowest-index tie-break).
// Phase C: coalesced v-row gather + atomicAdd into out_pre.
// ---------------------------------------------------------------------------
__global__ __launch_bounds__(64) void tok_fused(const float* __restrict__ qt,
                                                const float* __restrict__ kT,
                                                const float* __restrict__ v,
                                                const int* __restrict__ cnt,
                                                const int* __restrict__ list,
                                                const float* __restrict__ sel_w,
                                                float* __restrict__ out_pre)
{
    const int slot  = blockIdx.x;
    const int bsIdx = slot & 511;      // bin fast -> heavy chunk-0 blocks spread first
    const int chunk = slot >> 9;
    const int b  = bsIdx & 7;          // batch fast -> XCD spread
    const int s  = bsIdx >> 3;
    const int bs = b * SN + s;
    const int nq = cnt[bs];
    const int q0 = chunk * 64;
    if (q0 >= nq) return;
    const int nhere = min(64, nq - q0);

    __shared__ float sl[128 * 64];     // 32 KB score tile, [t][q ^ (t&63)]
    __shared__ int   pvi[TOK_K * 64];  // [j][q]
    __shared__ float pvw[TOK_K * 64];
    __shared__ int   qr[64];

    const int lane = threadIdx.x;
    const int half = lane >> 5;
    const int tg   = lane & 31;
    const float* kb = kT + ((size_t)bs << 14);

    // ---- Phase A: 4 rounds x 16 queries, GEMM layout ----
    for (int r = 0; r < 4; ++r) {
        const int qb = r * 16 + half * 8;
        int qrow[8];
        #pragma unroll
        for (int i = 0; i < 8; ++i) {
            int e = list[bs * 512 + min(q0 + qb + i, nq - 1)];   // clamp: dup row
            qrow[i] = e & 0xffff;
        }
        float acc[8][4];
        #pragma unroll
        for (int i = 0; i < 8; ++i)
            #pragma unroll
            for (int j = 0; j < 4; ++j) acc[i][j] = 0.f;

        #pragma unroll 2
        for (int dq = 0; dq < 128; dq += 4) {
            f4 kf[4];
            #pragma unroll
            for (int kk = 0; kk < 4; ++kk)
                kf[kk] = *(const f4*)(kb + (size_t)(dq + kk) * 128 + tg * 4);
            f4 qv[8];
            #pragma unroll
            for (int i = 0; i < 8; ++i)
                qv[i] = *(const f4*)(qt + ((size_t)(b * QN + qrow[i])) * 128 + dq);
            #pragma unroll
            for (int i = 0; i < 8; ++i)
                #pragma unroll
                for (int kk = 0; kk < 4; ++kk)
                    #pragma unroll
                    for (int j = 0; j < 4; ++j)
                        acc[i][j] = fmaf(qv[i][kk], kf[kk][j], acc[i][j]);
        }
        #pragma unroll
        for (int i = 0; i < 8; ++i) {
            int q = qb + i;
            #pragma unroll
            for (int j = 0; j < 4; ++j) {
                int t = tg * 4 + j;
                sl[t * 64 + (q ^ (t & 63))] = acc[i][j] * SCALE;
            }
        }
    }
    // Single wave per block: LDS ops complete in order for a wave; no barrier.

    // ---- Phase B: per-lane top-16 insertion, lane = query slot ----
    const int q = lane;
    float tv[TOK_K];
    int   ti[TOK_K];
    #pragma unroll
    for (int j = 0; j < TOK_K; ++j) { tv[j] = NINF; ti[j] = 0; }

    #pragma unroll 4
    for (int t = 0; t < 128; ++t) {
        float x = sl[t * 64 + (q ^ (t & 63))];
        int xi = t;
        #pragma unroll
        for (int j = 0; j < TOK_K; ++j) {
            bool swp = x > tv[j];               // strict: earlier index stays ahead
            float vn = swp ? x : tv[j];
            float vo = swp ? tv[j] : x;
            int in_ = swp ? xi : ti[j];
            int io  = swp ? ti[j] : xi;
            tv[j] = vn; x = vo;
            ti[j] = in_; xi = io;
        }
    }

    float m = tv[0];
    float Z = 0.f;
    float pw[TOK_K];
    #pragma unroll
    for (int j = 0; j < TOK_K; ++j) { pw[j] = expf(tv[j] - m); Z += pw[j]; }

    int e2 = list[bs * 512 + min(q0 + q, nq - 1)];
    int qrow2 = e2 & 0xffff, sidx2 = (e2 >> 16) & 7;
    float sww = sel_w[((size_t)(b * QN + qrow2)) * STAT_K + sidx2];
    float cs = sww / Z;                          // fold stat weight in
    qr[q] = qrow2;
    #pragma unroll
    for (int j = 0; j < TOK_K; ++j) {
        pvi[j * 64 + q] = ti[j];
        pvw[j * 64 + q] = pw[j] * cs;
    }

    // ---- Phase C: PV gather + atomic accumulate ----
    const float* vb = v + ((size_t)bs << 14);
    for (int qp = 0; qp < 32; ++qp) {
        int qq = qp * 2 + half;
        if (qq >= nhere) continue;
        int orow = qr[qq];                       // half-uniform LDS broadcast
        f4 o = {0.f, 0.f, 0.f, 0.f};
        #pragma unroll
        for (int j = 0; j < TOK_K; ++j) {
            int tok  = pvi[j * 64 + qq];
            float w  = pvw[j * 64 + qq];
            f4 vr = *(const f4*)(vb + (size_t)tok * 128 + tg * 4);
            o[0] = fmaf(w, vr[0], o[0]);
            o[1] = fmaf(w, vr[1], o[1]);
            o[2] = fmaf(w, vr[2], o[2]);
            o[3] = fmaf(w, vr[3], o[3]);
        }
        float* op = out_pre + ((size_t)(b * QN + orow)) * 128 + tg * 4;
        atomicAdd(op + 0, o[0]);
        atomicAdd(op + 1, o[1]);
        atomicAdd(op + 2, o[2]);
        atomicAdd(op + 3, o[3]);
    }
}

// ---------------------------------------------------------------------------
extern "C" void kernel_launch(void* const* d_in, const int* in_sizes, int n_in,
                              void* d_out, int out_size, void* d_ws, size_t ws_size,
                              hipStream_t stream)
{
    const float* queries    = (const float*)d_in[0];
    const float* stat_keys  = (const float*)d_in[1];
    const float* token_keys = (const float*)d_in[2];
    const float* values     = (const float*)d_in[3];
    const int*   vlen       = (const int*)d_in[4];
    const float* Wq_stat    = (const float*)d_in[5];
    const float* Wq_token   = (const float*)d_in[6];
    const float* Wk_stat    = (const float*)d_in[7];
    const float* Wk_token   = (const float*)d_in[8];
    const float* Wv         = (const float*)d_in[9];
    const float* Wo         = (const float*)d_in[10];

    char* ws = (char*)d_ws;
    float* q_stat  = (float*)(ws);                 // 2 MB (dead after stat_topk)
    int*   list    = (int*)  (ws);                 // 1 MB, overlays q_stat
    float* q_tok   = (float*)(ws + 2097152);       // 2 MB
    float* k_stat  = (float*)(ws + 4194304);       // 256 KB (dead after stat_topk)
    int*   cnt     = (int*)  (ws + 4194304);       // 2 KB, overlays k_stat
    float* k_tokT  = (float*)(ws + 4456448);       // [512][128d][128t] = 32 MB
    float* v       = (float*)(ws + 38010880);      // 32 MB
    int*   sel_i   = (int*)  (ws + 71565312);      // 128 KB
    float* sel_w   = (float*)(ws + 71696384);      // 128 KB
    float* out_pre = (float*)(ws + 71827456);      // 2 MB  (total 73,924,608 B)

    // Projections (fp32 exact: scores feed top-k)
    proj4_small<<<136,  256, 0, stream>>>(queries, stat_keys, Wq_stat, Wq_token,
                                          Wk_stat, q_stat, q_tok, k_stat);
    proj8_fused<<<1024, 256, 0, stream>>>(token_keys, values, Wk_token, Wv, k_tokT, v);

    // Stat-level top-8 selection + weights
    stat_topk<<<BB * QN, 64, 0, stream>>>(q_stat, k_stat, vlen, sel_i, sel_w);

    // Zero accumulators/counters (cnt overlays dead k_stat), bin queries
    zero_misc<<<512, 256, 0, stream>>>(out_pre, cnt);
    bin_build<<<128, 256, 0, stream>>>(sel_i, sel_w, cnt, list);

    // Token-level: one wave per (bin, 64-query chunk)
    tok_fused<<<4096, 64, 0, stream>>>(q_tok, k_tokT, v, cnt, list, sel_w, out_pre);

    // Output projection
    proj4_one<<<64, 256, 0, stream>>>(out_pre, Wo, (float*)d_out);
}